// Round 1
// baseline (556.846 us; speedup 1.0000x reference)
//
#include <hip/hip_runtime.h>
#include <math.h>

// Problem constants
#define BB   8
#define HH   64
#define WW   64
#define HW   4096
#define DIM  256
#define CR   64
#define GC   32
#define NHD  4
#define HC   16
#define NTAP 9
#define BGN  16
#define NCLS 80

// workspace layout (float offsets)
#define OFF_QP   0u          // q planar   [B][64][H][W]        2,097,152
#define OFF_QT   2097152u    // q pix-major[B*HW][64]           2,097,152
#define OFF_KT   4194304u    // k pix-major[BG][HW][32]         2,097,152
#define OFF_VT   6291456u    // v pix-major[BG][HW][32]         2,097,152
#define OFF_T    8388608u    // t planar   [BG][32][H][W]       2,097,152
#define OFF_OFFB 10485760u   // off planar [BG][18][H][W]       1,179,648
#define OFF_AOT  11665408u   // attn out   [64][B*HW] planar    2,097,152
// total 13,762,560 floats = 52.5 MB

// ---------------- Kernel 1: LN(channel) + QKV projection ----------------
// grid 512 (b*64+row), block 256. Wave og in {0,1,2,3} computes 48 output rows.
__global__ __launch_bounds__(256) void k1_ln_qkv(
    const float* __restrict__ x, const float* __restrict__ g1, const float* __restrict__ b1,
    const float* __restrict__ wqkv, float* __restrict__ ws)
{
    __shared__ float psum[256], psq[256], sm[64], srs[64];
    const int t = threadIdx.x;
    const int blk = blockIdx.x;
    const int b = blk >> 6, row = blk & 63;
    const int p = t & 63, q4 = t >> 6;
    const int colbase = row * 64 + p;

    // per-pixel LN stats over 256 channels (split across 4 waves)
    float s = 0.f, ss = 0.f;
    for (int i = 0; i < 64; ++i) {
        int c = q4 * 64 + i;
        float v = x[(size_t)(b * DIM + c) * HW + colbase];
        s += v; ss += v * v;
    }
    psum[t] = s; psq[t] = ss;
    __syncthreads();
    if (t < 64) {
        float S  = psum[t] + psum[64 + t] + psum[128 + t] + psum[192 + t];
        float SS = psq[t]  + psq[64 + t]  + psq[128 + t]  + psq[192 + t];
        float m  = S * (1.f / 256.f);
        float var = SS * (1.f / 256.f) - m * m;
        sm[t] = m; srs[t] = rsqrtf(var + 1e-5f);
    }
    __syncthreads();

    const int og = __builtin_amdgcn_readfirstlane(t >> 6); // wave-uniform -> s_load of weights
    const float mm = sm[p], rr = srs[p];
    float acc[48];
    #pragma unroll
    for (int j = 0; j < 48; ++j) acc[j] = 0.f;
    const int obase = og * 48;
    for (int c = 0; c < 256; ++c) {
        float xv = (x[(size_t)(b * DIM + c) * HW + colbase] - mm) * (rr * g1[c]) + b1[c];
        #pragma unroll
        for (int j = 0; j < 48; ++j)
            acc[j] += wqkv[(obase + j) * 256 + c] * xv;
    }

    float* qp = ws + OFF_QP; float* qt = ws + OFF_QT;
    float* kt = ws + OFF_KT; float* vt = ws + OFF_VT;
    #pragma unroll
    for (int j = 0; j < 48; ++j) {
        int o = obase + j;
        float v = acc[j];
        if (o < 64) {
            qp[(size_t)(b * 64 + o) * HW + colbase] = v;
            qt[((size_t)b * HW + colbase) * 64 + o] = v;
        } else if (o < 128) {
            int c = o - 64;
            kt[(((size_t)(b * 2 + (c >> 5)) * HW) + colbase) * 32 + (c & 31)] = v;
        } else {
            int c = o - 128;
            vt[(((size_t)(b * 2 + (c >> 5)) * HW) + colbase) * 32 + (c & 31)] = v;
        }
    }
}

// ------- Kernel 2: depthwise 3x3 conv + LN(32ch) + exact GELU -> t ------
// grid 256, block 256; one thread per (bg, pixel)
__global__ __launch_bounds__(256) void k2_off_feat(
    const float* __restrict__ wdw, const float* __restrict__ g2, const float* __restrict__ b2,
    float* __restrict__ ws)
{
    int tg = blockIdx.x * 256 + threadIdx.x;   // 0..65535
    int hw = tg & 4095, bg = tg >> 12;
    int h = hw >> 6, w = hw & 63;
    int b = bg >> 1, g = bg & 1;
    const float* qp = ws + OFF_QP;
    float vals[32];
    float s = 0.f, ssum = 0.f;
    #pragma unroll
    for (int ch = 0; ch < 32; ++ch) {
        float a = 0.f;
        const float* plane = qp + (size_t)(b * 64 + g * 32 + ch) * HW;
        #pragma unroll
        for (int dy = 0; dy < 3; ++dy) {
            int y = h + dy - 1;
            if ((unsigned)y >= 64u) continue;   // wave-uniform (h uniform per wave)
            #pragma unroll
            for (int dx = 0; dx < 3; ++dx) {
                int xx = w + dx - 1;
                bool v = (unsigned)xx < 64u;
                int xc = v ? xx : 0;
                float q = plane[y * 64 + xc];
                a += (v ? q : 0.f) * wdw[ch * 9 + dy * 3 + dx];
            }
        }
        vals[ch] = a; s += a; ssum += a * a;
    }
    float m = s * (1.f / 32.f);
    float var = ssum * (1.f / 32.f) - m * m;
    float rs = rsqrtf(var + 1e-5f);
    float* tb = ws + OFF_T;
    #pragma unroll
    for (int ch = 0; ch < 32; ++ch) {
        float u = (vals[ch] - m) * rs * g2[ch] + b2[ch];
        float ge = 0.5f * u * (1.f + erff(u * 0.70710678118654752f));
        tb[(size_t)(bg * 32 + ch) * HW + hw] = ge;
    }
}

// ------ Kernel 3: 3x3 conv 32->18 + bias, tanh*5 + base offset -> off ----
__global__ __launch_bounds__(256) void k3_pred_off(
    const float* __restrict__ woff, const float* __restrict__ boff,
    const float* __restrict__ off_in, float* __restrict__ ws)
{
    int tg = blockIdx.x * 256 + threadIdx.x;
    int hw = tg & 4095, bg = tg >> 12;
    int h = hw >> 6, w = hw & 63;
    int b = bg >> 1;
    const float* tb = ws + OFF_T;
    float acc[18];
    #pragma unroll
    for (int o = 0; o < 18; ++o) acc[o] = boff[o];
    for (int dy = 0; dy < 3; ++dy) {
        int y = h + dy - 1;
        if ((unsigned)y >= 64u) continue;
        for (int dx = 0; dx < 3; ++dx) {
            int xx = w + dx - 1;
            bool vld = (unsigned)xx < 64u;
            int xc = vld ? xx : 0;
            const float* tp = tb + (size_t)(bg * 32) * HW + y * 64 + xc;
            int wo = dy * 3 + dx;
            for (int ic = 0; ic < 32; ++ic) {
                float tv = tp[(size_t)ic * HW];
                tv = vld ? tv : 0.f;
                #pragma unroll
                for (int o = 0; o < 18; ++o)
                    acc[o] += tv * woff[(o * 32 + ic) * 9 + wo];
            }
        }
    }
    float* ob = ws + OFF_OFFB;
    #pragma unroll
    for (int o = 0; o < 18; ++o) {
        float v = tanhf(acc[o]) * 5.0f + off_in[(size_t)(b * 18 + o) * HW + hw];
        ob[(size_t)(bg * 18 + o) * HW + hw] = v;
    }
}

// ---- Kernel 4: deformable bilinear gather of K/V + online-softmax attn ----
// grid 512, block 256; one thread per (pixel, head)
__global__ __launch_bounds__(256) void k4_attn(
    const float* __restrict__ rpb, float* __restrict__ ws)
{
    __shared__ float rpb_l[NHD * NTAP * HC]; // 576 floats
    for (int i = threadIdx.x; i < NHD * NTAP * HC; i += 256) rpb_l[i] = rpb[i];
    __syncthreads();

    int tg = blockIdx.x * 256 + threadIdx.x;  // 0..131071
    int head = tg & 3, pix = tg >> 2;
    int b = pix >> 12, hw = pix & 4095;
    int g = head >> 1, sub = head & 1;
    int bg = b * 2 + g;
    const float* qt = ws + OFF_QT;
    const float* kt = ws + OFF_KT;
    const float* vt = ws + OFF_VT;
    const float* ob = ws + OFF_OFFB;

    float qv[16];
    #pragma unroll
    for (int i = 0; i < 16; ++i) qv[i] = qt[(size_t)pix * 64 + head * 16 + i] * 0.25f;

    float m = -INFINITY, l = 0.f, oacc[16];
    #pragma unroll
    for (int i = 0; i < 16; ++i) oacc[i] = 0.f;

    const size_t kvbase = (size_t)bg * HW * 32 + sub * 16;
    for (int n = 0; n < NTAP; ++n) {
        float r = ob[(size_t)(bg * 18 + 2 * n) * HW + hw];     // row (y)
        float c = ob[(size_t)(bg * 18 + 2 * n + 1) * HW + hw]; // col (x)
        float y0f = floorf(r), x0f = floorf(c);
        float fy = r - y0f, fx = c - x0f;
        int iy0 = (int)y0f, ix0 = (int)x0f;
        float wts[4] = { (1.f - fx) * (1.f - fy), fx * (1.f - fy),
                         (1.f - fx) * fy,         fx * fy };
        int cx[4] = { ix0, ix0 + 1, ix0, ix0 + 1 };
        int cy[4] = { iy0, iy0, iy0 + 1, iy0 + 1 };
        float ks[16], vs[16];
        #pragma unroll
        for (int i = 0; i < 16; ++i) { ks[i] = 0.f; vs[i] = 0.f; }
        #pragma unroll
        for (int corner = 0; corner < 4; ++corner) {
            bool vld = ((unsigned)cx[corner] < 64u) && ((unsigned)cy[corner] < 64u);
            if (!vld) continue;
            float wgt = wts[corner];
            size_t base = kvbase + (size_t)(cy[corner] * 64 + cx[corner]) * 32;
            const float4* kp = (const float4*)(kt + base);
            const float4* vp = (const float4*)(vt + base);
            #pragma unroll
            for (int j = 0; j < 4; ++j) {
                float4 kk = kp[j], vv = vp[j];
                ks[4 * j + 0] += wgt * kk.x; ks[4 * j + 1] += wgt * kk.y;
                ks[4 * j + 2] += wgt * kk.z; ks[4 * j + 3] += wgt * kk.w;
                vs[4 * j + 0] += wgt * vv.x; vs[4 * j + 1] += wgt * vv.y;
                vs[4 * j + 2] += wgt * vv.z; vs[4 * j + 3] += wgt * vv.w;
            }
        }
        float logit = 0.f;
        #pragma unroll
        for (int i = 0; i < 16; ++i)
            logit += qv[i] * (ks[i] + rpb_l[(head * 9 + n) * 16 + i]);
        float nm = fmaxf(m, logit);
        float alpha = __expf(m - nm);     // first iter: exp(-inf)=0
        float pexp  = __expf(logit - nm);
        l = l * alpha + pexp;
        #pragma unroll
        for (int i = 0; i < 16; ++i) oacc[i] = oacc[i] * alpha + pexp * vs[i];
        m = nm;
    }
    float inv = 1.f / l;
    float* ao = ws + OFF_AOT;
    #pragma unroll
    for (int i = 0; i < 16; ++i)
        ao[(size_t)(head * 16 + i) * (BB * HW) + pix] = oacc[i] * inv;
}

// ------ Kernel 5: proj(64->256)+bias+residual, then cls head (256->80) ----
// grid 512 (b*64+row), block 256, LDS 64 KB
__global__ __launch_bounds__(256) void k5_proj_cls(
    const float* __restrict__ x, const float* __restrict__ wproj, const float* __restrict__ bproj,
    const float* __restrict__ wcls, const float* __restrict__ bcls,
    const float* __restrict__ wsr, float* __restrict__ out)
{
    __shared__ float tmp[DIM * 64]; // tmp[c][p], 65536 B
    int t = threadIdx.x;
    int blk = blockIdx.x; int b = blk >> 6, row = blk & 63;
    int p = t & 63;
    int chunk = __builtin_amdgcn_readfirstlane(t >> 6);
    const float* ao = wsr + OFF_AOT;
    const int pixcol = row * 64 + p;

    // phase 1: tmp[c][p] = sum_cr ao[cr][pix] * wproj[c][cr] + bproj[c] + x[b][c][pix]
    for (int i8 = 0; i8 < 8; ++i8) {
        int cb = chunk * 64 + i8 * 8;
        float acc[8];
        #pragma unroll
        for (int j = 0; j < 8; ++j) acc[j] = 0.f;
        for (int cr = 0; cr < 64; ++cr) {
            float av = ao[(size_t)cr * (BB * HW) + (size_t)b * HW + pixcol];
            #pragma unroll
            for (int j = 0; j < 8; ++j)
                acc[j] += av * wproj[(cb + j) * 64 + cr];
        }
        #pragma unroll
        for (int j = 0; j < 8; ++j) {
            int c = cb + j;
            tmp[c * 64 + p] = acc[j] + bproj[c] + x[(size_t)(b * DIM + c) * HW + pixcol];
        }
    }
    __syncthreads();

    // phase 2: cls[cl] = sum_c tmp[c][p] * wcls[cl][c] + bcls[cl]
    float acc2[20];
    #pragma unroll
    for (int j = 0; j < 20; ++j) acc2[j] = bcls[chunk * 20 + j];
    for (int c = 0; c < 256; ++c) {
        float tv = tmp[c * 64 + p];
        #pragma unroll
        for (int j = 0; j < 20; ++j)
            acc2[j] += tv * wcls[(chunk * 20 + j) * 256 + c];
    }
    #pragma unroll
    for (int j = 0; j < 20; ++j) {
        int cl = chunk * 20 + j;
        out[(size_t)(b * NCLS + cl) * HW + pixcol] = acc2[j];
    }
}

extern "C" void kernel_launch(void* const* d_in, const int* in_sizes, int n_in,
                              void* d_out, int out_size, void* d_ws, size_t ws_size,
                              hipStream_t stream)
{
    const float* x     = (const float*)d_in[0];
    const float* off   = (const float*)d_in[1];
    const float* g1    = (const float*)d_in[2];
    const float* b1    = (const float*)d_in[3];
    const float* wqkv  = (const float*)d_in[4];
    const float* wdw   = (const float*)d_in[5];
    const float* g2    = (const float*)d_in[6];
    const float* b2    = (const float*)d_in[7];
    const float* woff  = (const float*)d_in[8];
    const float* boff  = (const float*)d_in[9];
    const float* rpb   = (const float*)d_in[10];
    const float* wproj = (const float*)d_in[11];
    const float* bproj = (const float*)d_in[12];
    const float* wcls  = (const float*)d_in[13];
    const float* bcls  = (const float*)d_in[14];
    float* ws  = (float*)d_ws;
    float* out = (float*)d_out;

    hipLaunchKernelGGL(k1_ln_qkv,   dim3(512), dim3(256), 0, stream, x, g1, b1, wqkv, ws);
    hipLaunchKernelGGL(k2_off_feat, dim3(256), dim3(256), 0, stream, wdw, g2, b2, ws);
    hipLaunchKernelGGL(k3_pred_off, dim3(256), dim3(256), 0, stream, woff, boff, off, ws);
    hipLaunchKernelGGL(k4_attn,     dim3(512), dim3(256), 0, stream, rpb, ws);
    hipLaunchKernelGGL(k5_proj_cls, dim3(512), dim3(256), 0, stream, x, wproj, bproj, wcls, bcls, ws, out);
}

// Round 2
// 365.391 us; speedup vs baseline: 1.5240x; 1.5240x over previous
//
#include <hip/hip_runtime.h>
#include <math.h>

// Problem constants
#define BB   8
#define HW   4096
#define BHW  32768
#define DIM  256
#define CR   64
#define GC   32
#define NHD  4
#define HC   16
#define NTAP 9
#define NCLS 80

// workspace layout (float offsets)
#define OFF_QP   0u          // q planar   [B][64][H][W]        2,097,152
#define OFF_QT   2097152u    // q pix-major[B*HW][64]           2,097,152
#define OFF_KT   4194304u    // k pix-major[BG][HW][32]         2,097,152
#define OFF_VT   6291456u    // v pix-major[BG][HW][32]         2,097,152
#define OFF_T    8388608u    // t planar   [BG][32][H][W]       2,097,152
// --- overlap region: these live inside OFF_T's span, used only BEFORE k2 writes T ---
#define OFF_WQT  8388608u    // wqkv^T * g1  [256][192]         49,152
#define OFF_AB   8437760u    // A[192], B[192]                  384
#define OFF_STAT 8438144u    // m[32768], rs[32768]             65,536 (ends 8,503,680 < 10,485,760)
// -------------------------------------------------------------------------------
#define OFF_OFFB 10485760u   // off planar [BG][18][H][W]       1,179,648
#define OFF_AOT  11665408u   // attn out   [64][B*HW] planar    2,097,152
#define OFF_WPT  13762560u   // wproj^T [64][256]               16,384
#define OFF_WCT  13778944u   // wcls^T  [256][80]               20,480
#define OFF_WFT  13799424u   // woff^T  [9][32][18]             5,184  (ends 13,804,608)

// ---------------- k0a: weight transposes ----------------
__global__ __launch_bounds__(256) void k0a_transpose(
    const float* __restrict__ wqkv, const float* __restrict__ g1,
    const float* __restrict__ wproj, const float* __restrict__ wcls,
    float* __restrict__ ws)
{
    const int c = blockIdx.x;   // 0..255
    const int t = threadIdx.x;
    if (t < 192) ws[OFF_WQT + c * 192 + t] = wqkv[t * 256 + c] * g1[c];
    if (c < 64)  ws[OFF_WPT + c * 256 + t] = wproj[t * 64 + c];
    if (t < 80)  ws[OFF_WCT + c * 80 + t]  = wcls[t * 256 + c];
}

// ---------------- k0b: A/B LN-fold vectors + woff transpose ----------------
__global__ __launch_bounds__(192) void k0b_ab(
    const float* __restrict__ wqkv, const float* __restrict__ g1,
    const float* __restrict__ b1, const float* __restrict__ woff,
    float* __restrict__ ws)
{
    const int t = threadIdx.x; // 0..191
    float a = 0.f, bb = 0.f;
    for (int c = 0; c < 256; ++c) {
        float w = wqkv[t * 256 + c];
        a += w * g1[c]; bb += w * b1[c];
    }
    ws[OFF_AB + t] = a;
    ws[OFF_AB + 192 + t] = bb;
    for (int pair = t; pair < 288; pair += 192) {
        int wo = pair >> 5, ic = pair & 31;
        for (int o = 0; o < 18; ++o)
            ws[OFF_WFT + (wo * 32 + ic) * 18 + o] = woff[(o * 32 + ic) * 9 + wo];
    }
}

// ---------------- k0c: per-pixel LN stats ----------------
__global__ __launch_bounds__(256) void k0c_stats(
    const float* __restrict__ x, float* __restrict__ ws)
{
    __shared__ float psum[256], psq[256];
    const int t = threadIdx.x;
    const int b = blockIdx.x >> 6, row = blockIdx.x & 63;
    const int p = t & 63, q4 = t >> 6;
    const int colbase = row * 64 + p;
    float s = 0.f, ss = 0.f;
    for (int i = 0; i < 64; ++i) {
        int c = q4 * 64 + i;
        float v = x[(size_t)(b * DIM + c) * HW + colbase];
        s += v; ss += v * v;
    }
    psum[t] = s; psq[t] = ss;
    __syncthreads();
    if (t < 64) {
        float S = psum[t] + psum[64 + t] + psum[128 + t] + psum[192 + t];
        float Q = psq[t] + psq[64 + t] + psq[128 + t] + psq[192 + t];
        float m = S * (1.f / 256.f);
        float v = Q * (1.f / 256.f) - m * m;
        float* stat = ws + OFF_STAT;
        int gp = b * HW + row * 64 + t;
        stat[gp] = m;
        stat[BHW + gp] = rsqrtf(v + 1e-5f);
    }
}

// ---------------- k1: QKV GEMM (LN folded into epilogue) ----------------
// grid 1024: mhalf=blk>>9 (96 outputs each), (b,row) = blk&511. block 256.
__global__ __launch_bounds__(256) void k1_gemm(
    const float* __restrict__ x, float* __restrict__ ws)
{
    __shared__ float xs[2][64 * 64];
    const int t = threadIdx.x;
    const int mhalf = blockIdx.x >> 9;
    const int rb = blockIdx.x & 511;
    const int b = rb >> 6, row = rb & 63;
    const int p = t & 63;
    const int og = __builtin_amdgcn_readfirstlane(t >> 6);
    const int obase = mhalf * 96 + og * 24;
    const float* wqT = ws + OFF_WQT;
    const float* AB  = ws + OFF_AB;
    const float* stat = ws + OFF_STAT;
    const size_t xbase = (size_t)b * DIM * HW + row * 64;

    float acc[24];
    #pragma unroll
    for (int j = 0; j < 24; ++j) acc[j] = 0.f;

    // stage K-tile 0
    #pragma unroll
    for (int j = 0; j < 4; ++j) {
        int idx4 = t + j * 256;
        int c = idx4 >> 4, p4 = (idx4 & 15) << 2;
        float4 v = *(const float4*)&x[xbase + (size_t)c * HW + p4];
        *(float4*)&xs[0][c * 64 + p4] = v;
    }
    __syncthreads();

    for (int kt = 0; kt < 4; ++kt) {
        const int cur = kt & 1;
        float4 pf[4];
        if (kt < 3) {
            #pragma unroll
            for (int j = 0; j < 4; ++j) {
                int idx4 = t + j * 256;
                int c = idx4 >> 4, p4 = (idx4 & 15) << 2;
                pf[j] = *(const float4*)&x[xbase + (size_t)((kt + 1) * 64 + c) * HW + p4];
            }
        }
        const float* wb = wqT + (size_t)kt * 64 * 192 + obase;
        #pragma unroll 8
        for (int c = 0; c < 64; ++c) {
            float xv = xs[cur][c * 64 + p];
            #pragma unroll
            for (int j = 0; j < 24; ++j)
                acc[j] += wb[c * 192 + j] * xv;
        }
        if (kt < 3) {
            #pragma unroll
            for (int j = 0; j < 4; ++j) {
                int idx4 = t + j * 256;
                int c = idx4 >> 4, p4 = (idx4 & 15) << 2;
                *(float4*)&xs[cur ^ 1][c * 64 + p4] = pf[j];
            }
            __syncthreads();
        }
    }

    // epilogue: apply LN fold, scatter to q/k/v layouts
    const int colbase = row * 64 + p;
    const int gp = b * HW + colbase;
    const float m = stat[gp], rsv = stat[BHW + gp];
    float* qp = ws + OFF_QP; float* qt = ws + OFF_QT;
    float* ktb = ws + OFF_KT; float* vtb = ws + OFF_VT;
    #pragma unroll
    for (int j = 0; j < 24; ++j) {
        int o = obase + j;
        float val = rsv * (acc[j] - m * AB[o]) + AB[192 + o];
        if (o < 64) {
            qp[(size_t)(b * 64 + o) * HW + colbase] = val;
            qt[((size_t)b * HW + colbase) * 64 + o] = val;
        } else if (o < 128) {
            int c2 = o - 64;
            ktb[(((size_t)(b * 2 + (c2 >> 5)) * HW) + colbase) * 32 + (c2 & 31)] = val;
        } else {
            int c2 = o - 128;
            vtb[(((size_t)(b * 2 + (c2 >> 5)) * HW) + colbase) * 32 + (c2 & 31)] = val;
        }
    }
}

// ------- k2: depthwise 3x3 + LN(32) + GELU, channel-split across waves -------
// grid 1024 (bg*64+row), block 256: p = t&63, cq = t>>6 owns 8 channels
__global__ __launch_bounds__(256) void k2_off_feat(
    const float* __restrict__ wdw, const float* __restrict__ g2, const float* __restrict__ b2,
    float* __restrict__ ws)
{
    __shared__ float rsum[4][64], rsq[4][64], smv[64], srv[64];
    const int t = threadIdx.x;
    const int bg = blockIdx.x >> 6, row = blockIdx.x & 63;
    const int p = t & 63;
    const int cq = __builtin_amdgcn_readfirstlane(t >> 6);
    const int b = bg >> 1, g = bg & 1;
    const float* qp = ws + OFF_QP;
    float vals[8];
    float s = 0.f, ss = 0.f;
    #pragma unroll
    for (int i = 0; i < 8; ++i) {
        int ch = cq * 8 + i;
        const float* plane = qp + (size_t)(b * 64 + g * 32 + ch) * HW;
        float a = 0.f;
        #pragma unroll
        for (int dy = 0; dy < 3; ++dy) {
            int y = row + dy - 1;
            if ((unsigned)y >= 64u) continue;
            #pragma unroll
            for (int dx = 0; dx < 3; ++dx) {
                int xx = p + dx - 1;
                bool vld = (unsigned)xx < 64u;
                float q = plane[y * 64 + (vld ? xx : 0)];
                a += (vld ? q : 0.f) * wdw[ch * 9 + dy * 3 + dx];
            }
        }
        vals[i] = a; s += a; ss += a * a;
    }
    rsum[cq][p] = s; rsq[cq][p] = ss;
    __syncthreads();
    if (t < 64) {
        float S = rsum[0][t] + rsum[1][t] + rsum[2][t] + rsum[3][t];
        float Q = rsq[0][t] + rsq[1][t] + rsq[2][t] + rsq[3][t];
        float m = S * (1.f / 32.f);
        float v = Q * (1.f / 32.f) - m * m;
        smv[t] = m; srv[t] = rsqrtf(v + 1e-5f);
    }
    __syncthreads();
    float m = smv[p], rv = srv[p];
    float* tb = ws + OFF_T;
    #pragma unroll
    for (int i = 0; i < 8; ++i) {
        int ch = cq * 8 + i;
        float u = (vals[i] - m) * rv * g2[ch] + b2[ch];
        float ge = 0.5f * u * (1.f + erff(u * 0.70710678118654752f));
        tb[(size_t)(bg * 32 + ch) * HW + row * 64 + p] = ge;
    }
}

// ------- k3: 3x3 conv 32->18 + tanh*5 + base offset, ic-split across waves -------
// grid 1024 (bg*64+row), block 256: p = t&63, icq = t>>6 owns 8 input channels
__global__ __launch_bounds__(256) void k3_pred_off(
    const float* __restrict__ boff, const float* __restrict__ off_in,
    float* __restrict__ ws)
{
    __shared__ float part[4 * 18 * 64];
    const int t = threadIdx.x;
    const int bg = blockIdx.x >> 6, row = blockIdx.x & 63;
    const int p = t & 63;
    const int icq = __builtin_amdgcn_readfirstlane(t >> 6);
    const int b = bg >> 1;
    const float* tb = ws + OFF_T;
    const float* wfT = ws + OFF_WFT;
    float acc[18];
    #pragma unroll
    for (int o = 0; o < 18; ++o) acc[o] = 0.f;
    #pragma unroll
    for (int dy = 0; dy < 3; ++dy) {
        int y = row + dy - 1;
        if ((unsigned)y >= 64u) continue;
        #pragma unroll
        for (int dx = 0; dx < 3; ++dx) {
            int xx = p + dx - 1;
            bool vld = (unsigned)xx < 64u;
            int xc = vld ? xx : 0;
            int wo = dy * 3 + dx;
            #pragma unroll
            for (int i = 0; i < 8; ++i) {
                int ic = icq * 8 + i;
                float tv = tb[(size_t)(bg * 32 + ic) * HW + y * 64 + xc];
                tv = vld ? tv : 0.f;
                const float* wrow = wfT + (wo * 32 + ic) * 18;
                #pragma unroll
                for (int o = 0; o < 18; ++o)
                    acc[o] += tv * wrow[o];
            }
        }
    }
    #pragma unroll
    for (int o = 0; o < 18; ++o) part[(icq * 18 + o) * 64 + p] = acc[o];
    __syncthreads();
    float* ob = ws + OFF_OFFB;
    #pragma unroll
    for (int r = 0; r < 5; ++r) {
        int idx = t + r * 256;
        if (idx < 1152) {
            int o = idx >> 6, p2 = idx & 63;
            float v = part[o * 64 + p2] + part[(18 + o) * 64 + p2]
                    + part[(36 + o) * 64 + p2] + part[(54 + o) * 64 + p2] + boff[o];
            v = tanhf(v) * 5.0f + off_in[(size_t)(b * 18 + o) * HW + row * 64 + p2];
            ob[(size_t)(bg * 18 + o) * HW + row * 64 + p2] = v;
        }
    }
}

// ---- k4: deformable bilinear gather of K/V + online-softmax attn (unchanged) ----
__global__ __launch_bounds__(256) void k4_attn(
    const float* __restrict__ rpb, float* __restrict__ ws)
{
    __shared__ float rpb_l[NHD * NTAP * HC];
    for (int i = threadIdx.x; i < NHD * NTAP * HC; i += 256) rpb_l[i] = rpb[i];
    __syncthreads();

    int tg = blockIdx.x * 256 + threadIdx.x;  // 0..131071
    int head = tg & 3, pix = tg >> 2;
    int b = pix >> 12, hw = pix & 4095;
    int g = head >> 1, sub = head & 1;
    int bg = b * 2 + g;
    const float* qt = ws + OFF_QT;
    const float* kt = ws + OFF_KT;
    const float* vt = ws + OFF_VT;
    const float* ob = ws + OFF_OFFB;

    float qv[16];
    #pragma unroll
    for (int i = 0; i < 16; ++i) qv[i] = qt[(size_t)pix * 64 + head * 16 + i] * 0.25f;

    float m = -INFINITY, l = 0.f, oacc[16];
    #pragma unroll
    for (int i = 0; i < 16; ++i) oacc[i] = 0.f;

    const size_t kvbase = (size_t)bg * HW * 32 + sub * 16;
    for (int n = 0; n < NTAP; ++n) {
        float r = ob[(size_t)(bg * 18 + 2 * n) * HW + hw];
        float c = ob[(size_t)(bg * 18 + 2 * n + 1) * HW + hw];
        float y0f = floorf(r), x0f = floorf(c);
        float fy = r - y0f, fx = c - x0f;
        int iy0 = (int)y0f, ix0 = (int)x0f;
        float wts[4] = { (1.f - fx) * (1.f - fy), fx * (1.f - fy),
                         (1.f - fx) * fy,         fx * fy };
        int cx[4] = { ix0, ix0 + 1, ix0, ix0 + 1 };
        int cy[4] = { iy0, iy0, iy0 + 1, iy0 + 1 };
        float ks[16], vs[16];
        #pragma unroll
        for (int i = 0; i < 16; ++i) { ks[i] = 0.f; vs[i] = 0.f; }
        #pragma unroll
        for (int corner = 0; corner < 4; ++corner) {
            bool vld = ((unsigned)cx[corner] < 64u) && ((unsigned)cy[corner] < 64u);
            if (!vld) continue;
            float wgt = wts[corner];
            size_t base = kvbase + (size_t)(cy[corner] * 64 + cx[corner]) * 32;
            const float4* kp = (const float4*)(kt + base);
            const float4* vp = (const float4*)(vt + base);
            #pragma unroll
            for (int j = 0; j < 4; ++j) {
                float4 kk = kp[j], vv = vp[j];
                ks[4 * j + 0] += wgt * kk.x; ks[4 * j + 1] += wgt * kk.y;
                ks[4 * j + 2] += wgt * kk.z; ks[4 * j + 3] += wgt * kk.w;
                vs[4 * j + 0] += wgt * vv.x; vs[4 * j + 1] += wgt * vv.y;
                vs[4 * j + 2] += wgt * vv.z; vs[4 * j + 3] += wgt * vv.w;
            }
        }
        float logit = 0.f;
        #pragma unroll
        for (int i = 0; i < 16; ++i)
            logit += qv[i] * (ks[i] + rpb_l[(head * 9 + n) * 16 + i]);
        float nm = fmaxf(m, logit);
        float alpha = __expf(m - nm);
        float pexp  = __expf(logit - nm);
        l = l * alpha + pexp;
        #pragma unroll
        for (int i = 0; i < 16; ++i) oacc[i] = oacc[i] * alpha + pexp * vs[i];
        m = nm;
    }
    float inv = 1.f / l;
    float* ao = ws + OFF_AOT;
    #pragma unroll
    for (int i = 0; i < 16; ++i)
        ao[(size_t)(head * 16 + i) * BHW + pix] = oacc[i] * inv;
}

// ------ k5: proj(64->256)+bias+residual, then cls head (256->80) ----
// grid 512 (b*64+row), block 256, LDS 64 KB
__global__ __launch_bounds__(256) void k5_proj_cls(
    const float* __restrict__ x, const float* __restrict__ bproj,
    const float* __restrict__ bcls, const float* __restrict__ wsr, float* __restrict__ out)
{
    __shared__ float tmp[DIM * 64];
    const int t = threadIdx.x;
    const int b = blockIdx.x >> 6, row = blockIdx.x & 63;
    const int p = t & 63;
    const int chunk = __builtin_amdgcn_readfirstlane(t >> 6);
    const float* ao  = wsr + OFF_AOT;
    const float* wpT = wsr + OFF_WPT;
    const float* wcT = wsr + OFF_WCT;
    const int pixcol = row * 64 + p;
    const int cb = chunk * 64;

    float acc[64];
    #pragma unroll
    for (int j = 0; j < 64; ++j) acc[j] = 0.f;
    const size_t aob = (size_t)b * HW + pixcol;
    #pragma unroll 4
    for (int cr = 0; cr < 64; ++cr) {
        float av = ao[(size_t)cr * BHW + aob];
        const float* wrow = wpT + cr * 256 + cb;
        #pragma unroll
        for (int j = 0; j < 64; ++j)
            acc[j] += av * wrow[j];
    }
    #pragma unroll
    for (int j = 0; j < 64; ++j) {
        int c = cb + j;
        tmp[c * 64 + p] = acc[j] + bproj[c] + x[(size_t)(b * DIM + c) * HW + pixcol];
    }
    __syncthreads();

    float acc2[20];
    #pragma unroll
    for (int j = 0; j < 20; ++j) acc2[j] = bcls[chunk * 20 + j];
    #pragma unroll 4
    for (int c = 0; c < 256; ++c) {
        float tv = tmp[c * 64 + p];
        const float* wrow = wcT + c * 80 + chunk * 20;
        #pragma unroll
        for (int j = 0; j < 20; ++j)
            acc2[j] += tv * wrow[j];
    }
    #pragma unroll
    for (int j = 0; j < 20; ++j)
        out[(size_t)(b * NCLS + chunk * 20 + j) * HW + pixcol] = acc2[j];
}

extern "C" void kernel_launch(void* const* d_in, const int* in_sizes, int n_in,
                              void* d_out, int out_size, void* d_ws, size_t ws_size,
                              hipStream_t stream)
{
    const float* x     = (const float*)d_in[0];
    const float* off   = (const float*)d_in[1];
    const float* g1    = (const float*)d_in[2];
    const float* b1    = (const float*)d_in[3];
    const float* wqkv  = (const float*)d_in[4];
    const float* wdw   = (const float*)d_in[5];
    const float* g2    = (const float*)d_in[6];
    const float* b2    = (const float*)d_in[7];
    const float* woff  = (const float*)d_in[8];
    const float* boff  = (const float*)d_in[9];
    const float* rpb   = (const float*)d_in[10];
    const float* wproj = (const float*)d_in[11];
    const float* bproj = (const float*)d_in[12];
    const float* wcls  = (const float*)d_in[13];
    const float* bcls  = (const float*)d_in[14];
    float* ws  = (float*)d_ws;
    float* out = (float*)d_out;

    hipLaunchKernelGGL(k0a_transpose, dim3(256), dim3(256), 0, stream, wqkv, g1, wproj, wcls, ws);
    hipLaunchKernelGGL(k0b_ab,        dim3(1),   dim3(192), 0, stream, wqkv, g1, b1, woff, ws);
    hipLaunchKernelGGL(k0c_stats,     dim3(512), dim3(256), 0, stream, x, ws);
    hipLaunchKernelGGL(k1_gemm,       dim3(1024), dim3(256), 0, stream, x, ws);
    hipLaunchKernelGGL(k2_off_feat,   dim3(1024), dim3(256), 0, stream, wdw, g2, b2, ws);
    hipLaunchKernelGGL(k3_pred_off,   dim3(1024), dim3(256), 0, stream, boff, off, ws);
    hipLaunchKernelGGL(k4_attn,       dim3(512), dim3(256), 0, stream, rpb, ws);
    hipLaunchKernelGGL(k5_proj_cls,   dim3(512), dim3(256), 0, stream, x, bproj, bcls, ws, out);
}

// Round 3
// 342.663 us; speedup vs baseline: 1.6251x; 1.0663x over previous
//
#include <hip/hip_runtime.h>
#include <math.h>

// Problem constants
#define BB   8
#define HW   4096
#define BHW  32768
#define DIM  256
#define CR   64
#define GC   32
#define NHD  4
#define HC   16
#define NTAP 9
#define NCLS 80

// workspace layout (float offsets)
#define OFF_QP   0u          // q planar   [B][64][H][W]        2,097,152
#define OFF_QT   2097152u    // (unused now)                    2,097,152
#define OFF_KT   4194304u    // k pix-major[BG][HW][32]         2,097,152
#define OFF_VT   6291456u    // v pix-major[BG][HW][32]         2,097,152
#define OFF_T    8388608u    // t planar   [BG][32][H][W]       2,097,152
// --- overlap region: inside OFF_T's span, used only BEFORE k2 writes T ---
#define OFF_WQT  8388608u    // wqkv^T * g1  [256][192]         49,152
#define OFF_AB   8437760u    // A[192], B[192]                  384
#define OFF_STAT 8438144u    // m[32768], rs[32768]             65,536
// ------------------------------------------------------------------------
#define OFF_OFFB 10485760u   // off planar [BG][18][H][W]       1,179,648
#define OFF_AOT  11665408u   // attn out   [64][B*HW] planar    2,097,152
#define OFF_WPT  13762560u   // wproj^T [64][256]               16,384
#define OFF_WCT  13778944u   // wcls^T  [256][80]               20,480
#define OFF_WFT  13799424u   // woff^T  [9][32][18]             5,184

// ---------------- k0a: weight transposes ----------------
__global__ __launch_bounds__(256) void k0a_transpose(
    const float* __restrict__ wqkv, const float* __restrict__ g1,
    const float* __restrict__ wproj, const float* __restrict__ wcls,
    float* __restrict__ ws)
{
    const int c = blockIdx.x;   // 0..255
    const int t = threadIdx.x;
    if (t < 192) ws[OFF_WQT + c * 192 + t] = wqkv[t * 256 + c] * g1[c];
    if (c < 64)  ws[OFF_WPT + c * 256 + t] = wproj[t * 64 + c];
    if (t < 80)  ws[OFF_WCT + c * 80 + t]  = wcls[t * 256 + c];
}

// ---------------- k0b: A/B LN-fold vectors + woff transpose ----------------
__global__ __launch_bounds__(192) void k0b_ab(
    const float* __restrict__ wqkv, const float* __restrict__ g1,
    const float* __restrict__ b1, const float* __restrict__ woff,
    float* __restrict__ ws)
{
    const int t = threadIdx.x; // 0..191
    float a = 0.f, bb = 0.f;
    for (int c = 0; c < 256; ++c) {
        float w = wqkv[t * 256 + c];
        a += w * g1[c]; bb += w * b1[c];
    }
    ws[OFF_AB + t] = a;
    ws[OFF_AB + 192 + t] = bb;
    for (int pair = t; pair < 288; pair += 192) {
        int wo = pair >> 5, ic = pair & 31;
        for (int o = 0; o < 18; ++o)
            ws[OFF_WFT + (wo * 32 + ic) * 18 + o] = woff[(o * 32 + ic) * 9 + wo];
    }
}

// ---------------- k0c: per-pixel LN stats ----------------
__global__ __launch_bounds__(256) void k0c_stats(
    const float* __restrict__ x, float* __restrict__ ws)
{
    __shared__ float psum[256], psq[256];
    const int t = threadIdx.x;
    const int b = blockIdx.x >> 6, row = blockIdx.x & 63;
    const int p = t & 63, q4 = t >> 6;
    const int colbase = row * 64 + p;
    float s = 0.f, ss = 0.f;
    for (int i = 0; i < 64; ++i) {
        int c = q4 * 64 + i;
        float v = x[(size_t)(b * DIM + c) * HW + colbase];
        s += v; ss += v * v;
    }
    psum[t] = s; psq[t] = ss;
    __syncthreads();
    if (t < 64) {
        float S = psum[t] + psum[64 + t] + psum[128 + t] + psum[192 + t];
        float Q = psq[t] + psq[64 + t] + psq[128 + t] + psq[192 + t];
        float m = S * (1.f / 256.f);
        float v = Q * (1.f / 256.f) - m * m;
        float* stat = ws + OFF_STAT;
        int gp = b * HW + row * 64 + t;
        stat[gp] = m;
        stat[BHW + gp] = rsqrtf(v + 1e-5f);
    }
}

// ---------------- k1: QKV GEMM (LN folded; coalesced epilogue) ----------------
// grid 1024: mhalf=blk>>9 (96 outputs each), (b,row)=blk&511. block 256.
__global__ __launch_bounds__(256) void k1_gemm(
    const float* __restrict__ x, float* __restrict__ ws)
{
    __shared__ float smem[8192];     // 2x 16KB staging; reused as 64x97 transpose tile
    const int t = threadIdx.x;
    const int mhalf = blockIdx.x >> 9;
    const int rb = blockIdx.x & 511;
    const int b = rb >> 6, row = rb & 63;
    const int p = t & 63;
    const int og = __builtin_amdgcn_readfirstlane(t >> 6);
    const int obase = mhalf * 96 + og * 24;
    const float* wqT = ws + OFF_WQT;
    const float* AB  = ws + OFF_AB;
    const float* stat = ws + OFF_STAT;
    const size_t xbase = (size_t)b * DIM * HW + row * 64;

    float acc[24];
    #pragma unroll
    for (int j = 0; j < 24; ++j) acc[j] = 0.f;

    // stage K-tile 0
    #pragma unroll
    for (int j = 0; j < 4; ++j) {
        int idx4 = t + j * 256;
        int c = idx4 >> 4, p4 = (idx4 & 15) << 2;
        float4 v = *(const float4*)&x[xbase + (size_t)c * HW + p4];
        *(float4*)&smem[c * 64 + p4] = v;
    }
    __syncthreads();

    for (int kt = 0; kt < 4; ++kt) {
        const int cur = kt & 1;
        float4 pf[4];
        if (kt < 3) {
            #pragma unroll
            for (int j = 0; j < 4; ++j) {
                int idx4 = t + j * 256;
                int c = idx4 >> 4, p4 = (idx4 & 15) << 2;
                pf[j] = *(const float4*)&x[xbase + (size_t)((kt + 1) * 64 + c) * HW + p4];
            }
        }
        const float* wb = wqT + (size_t)kt * 64 * 192 + obase;
        #pragma unroll 8
        for (int c = 0; c < 64; ++c) {
            float xv = smem[cur * 4096 + c * 64 + p];
            #pragma unroll
            for (int j = 0; j < 24; ++j)
                acc[j] += wb[c * 192 + j] * xv;
        }
        if (kt < 3) {
            #pragma unroll
            for (int j = 0; j < 4; ++j) {
                int idx4 = t + j * 256;
                int c = idx4 >> 4, p4 = (idx4 & 15) << 2;
                *(float4*)&smem[(cur ^ 1) * 4096 + c * 64 + p4] = pf[j];
            }
            __syncthreads();
        }
    }
    __syncthreads();   // everyone done reading staging LDS

    // LN fold + write into transpose tile [64 px][96 ch] (pad 97)
    const int colbase = row * 64 + p;
    const int gp = b * HW + colbase;
    const float m = stat[gp], rsv = stat[BHW + gp];
    #pragma unroll
    for (int j = 0; j < 24; ++j) {
        int o = obase + j;
        smem[p * 97 + og * 24 + j] = rsv * (acc[j] - m * AB[o]) + AB[192 + o];
    }
    __syncthreads();

    float* qp  = ws + OFF_QP;
    float* ktb = ws + OFF_KT;
    float* vtb = ws + OFF_VT;
    const int colrow = row * 64;
    if (mhalf == 0) {
        // q planar: o in [0,64)
        #pragma unroll
        for (int it = 0; it < 16; ++it) {
            int idx = it * 256 + t;
            int o = idx >> 6, px = idx & 63;
            qp[(size_t)(b * 64 + o) * HW + colrow + px] = smem[px * 97 + o];
        }
        // k group 0: local ch 64..95
        #pragma unroll
        for (int it = 0; it < 8; ++it) {
            int idx = it * 256 + t;
            int px = idx >> 5, ch = idx & 31;
            ktb[(((size_t)(b * 2) * HW) + colrow + px) * 32 + ch] = smem[px * 97 + 64 + ch];
        }
    } else {
        // k group 1: local 0..31; v group 0: 32..63; v group 1: 64..95
        #pragma unroll
        for (int it = 0; it < 8; ++it) {
            int idx = it * 256 + t;
            int px = idx >> 5, ch = idx & 31;
            ktb[(((size_t)(b * 2 + 1) * HW) + colrow + px) * 32 + ch] = smem[px * 97 + ch];
        }
        #pragma unroll
        for (int it = 0; it < 8; ++it) {
            int idx = it * 256 + t;
            int px = idx >> 5, ch = idx & 31;
            vtb[(((size_t)(b * 2) * HW) + colrow + px) * 32 + ch] = smem[px * 97 + 32 + ch];
        }
        #pragma unroll
        for (int it = 0; it < 8; ++it) {
            int idx = it * 256 + t;
            int px = idx >> 5, ch = idx & 31;
            vtb[(((size_t)(b * 2 + 1) * HW) + colrow + px) * 32 + ch] = smem[px * 97 + 64 + ch];
        }
    }
}

// ------- k2: depthwise 3x3 + LN(32) + GELU, channel-split across waves -------
__global__ __launch_bounds__(256) void k2_off_feat(
    const float* __restrict__ wdw, const float* __restrict__ g2, const float* __restrict__ b2,
    float* __restrict__ ws)
{
    __shared__ float rsum[4][64], rsq[4][64], smv[64], srv[64];
    const int t = threadIdx.x;
    const int bg = blockIdx.x >> 6, row = blockIdx.x & 63;
    const int p = t & 63;
    const int cq = __builtin_amdgcn_readfirstlane(t >> 6);
    const int b = bg >> 1, g = bg & 1;
    const float* qp = ws + OFF_QP;
    float vals[8];
    float s = 0.f, ss = 0.f;
    #pragma unroll
    for (int i = 0; i < 8; ++i) {
        int ch = cq * 8 + i;
        const float* plane = qp + (size_t)(b * 64 + g * 32 + ch) * HW;
        float a = 0.f;
        #pragma unroll
        for (int dy = 0; dy < 3; ++dy) {
            int y = row + dy - 1;
            if ((unsigned)y >= 64u) continue;
            #pragma unroll
            for (int dx = 0; dx < 3; ++dx) {
                int xx = p + dx - 1;
                bool vld = (unsigned)xx < 64u;
                float q = plane[y * 64 + (vld ? xx : 0)];
                a += (vld ? q : 0.f) * wdw[ch * 9 + dy * 3 + dx];
            }
        }
        vals[i] = a; s += a; ss += a * a;
    }
    rsum[cq][p] = s; rsq[cq][p] = ss;
    __syncthreads();
    if (t < 64) {
        float S = rsum[0][t] + rsum[1][t] + rsum[2][t] + rsum[3][t];
        float Q = rsq[0][t] + rsq[1][t] + rsq[2][t] + rsq[3][t];
        float m = S * (1.f / 32.f);
        float v = Q * (1.f / 32.f) - m * m;
        smv[t] = m; srv[t] = rsqrtf(v + 1e-5f);
    }
    __syncthreads();
    float m = smv[p], rv = srv[p];
    float* tb = ws + OFF_T;
    #pragma unroll
    for (int i = 0; i < 8; ++i) {
        int ch = cq * 8 + i;
        float u = (vals[i] - m) * rv * g2[ch] + b2[ch];
        float ge = 0.5f * u * (1.f + erff(u * 0.70710678118654752f));
        tb[(size_t)(bg * 32 + ch) * HW + row * 64 + p] = ge;
    }
}

// ------- k3: 3x3 conv 32->18 + tanh*5 + base offset, ic-split across waves -------
__global__ __launch_bounds__(256) void k3_pred_off(
    const float* __restrict__ boff, const float* __restrict__ off_in,
    float* __restrict__ ws)
{
    __shared__ float part[4 * 18 * 64];
    const int t = threadIdx.x;
    const int bg = blockIdx.x >> 6, row = blockIdx.x & 63;
    const int p = t & 63;
    const int icq = __builtin_amdgcn_readfirstlane(t >> 6);
    const int b = bg >> 1;
    const float* tb = ws + OFF_T;
    const float* wfT = ws + OFF_WFT;
    float acc[18];
    #pragma unroll
    for (int o = 0; o < 18; ++o) acc[o] = 0.f;
    #pragma unroll
    for (int dy = 0; dy < 3; ++dy) {
        int y = row + dy - 1;
        if ((unsigned)y >= 64u) continue;
        #pragma unroll
        for (int dx = 0; dx < 3; ++dx) {
            int xx = p + dx - 1;
            bool vld = (unsigned)xx < 64u;
            int xc = vld ? xx : 0;
            int wo = dy * 3 + dx;
            #pragma unroll
            for (int i = 0; i < 8; ++i) {
                int ic = icq * 8 + i;
                float tv = tb[(size_t)(bg * 32 + ic) * HW + y * 64 + xc];
                tv = vld ? tv : 0.f;
                const float* wrow = wfT + (wo * 32 + ic) * 18;
                #pragma unroll
                for (int o = 0; o < 18; ++o)
                    acc[o] += tv * wrow[o];
            }
        }
    }
    #pragma unroll
    for (int o = 0; o < 18; ++o) part[(icq * 18 + o) * 64 + p] = acc[o];
    __syncthreads();
    float* ob = ws + OFF_OFFB;
    #pragma unroll
    for (int r = 0; r < 5; ++r) {
        int idx = t + r * 256;
        if (idx < 1152) {
            int o = idx >> 6, p2 = idx & 63;
            float v = part[o * 64 + p2] + part[(18 + o) * 64 + p2]
                    + part[(36 + o) * 64 + p2] + part[(54 + o) * 64 + p2] + boff[o];
            v = tanhf(v) * 5.0f + off_in[(size_t)(b * 18 + o) * HW + row * 64 + p2];
            ob[(size_t)(bg * 18 + o) * HW + row * 64 + p2] = v;
        }
    }
}

// ---- k4: deformable gather + online-softmax attn; coalesced lane mapping ----
// grid 512, block 256: pix = blk*64 + (t&63) [lane-consecutive], head = t>>6
__global__ __launch_bounds__(256) void k4_attn(
    const float* __restrict__ rpb, float* __restrict__ ws)
{
    __shared__ float rpb_l[NHD * NTAP * HC];
    for (int i = threadIdx.x; i < NHD * NTAP * HC; i += 256) rpb_l[i] = rpb[i];
    __syncthreads();

    const int t = threadIdx.x;
    const int lanepix = t & 63;
    const int head = __builtin_amdgcn_readfirstlane(t >> 6);
    const int pix = blockIdx.x * 64 + lanepix;
    const int b = pix >> 12, hw = pix & 4095;
    const int g = head >> 1, sub = head & 1;
    const int bg = b * 2 + g;
    const float* qp = ws + OFF_QP;
    const float* kt = ws + OFF_KT;
    const float* vt = ws + OFF_VT;
    const float* ob = ws + OFF_OFFB;

    float qv[16];
    #pragma unroll
    for (int i = 0; i < 16; ++i)
        qv[i] = qp[(size_t)(b * 64 + head * 16 + i) * HW + hw] * 0.25f;

    float rr[NTAP], cc[NTAP];
    #pragma unroll
    for (int n = 0; n < NTAP; ++n) {
        rr[n] = ob[(size_t)(bg * 18 + 2 * n) * HW + hw];
        cc[n] = ob[(size_t)(bg * 18 + 2 * n + 1) * HW + hw];
    }

    float m = -INFINITY, l = 0.f, oacc[16];
    #pragma unroll
    for (int i = 0; i < 16; ++i) oacc[i] = 0.f;

    const size_t kvbase = (size_t)bg * HW * 32 + sub * 16;
    for (int n = 0; n < NTAP; ++n) {
        float r = rr[n], c = cc[n];
        float y0f = floorf(r), x0f = floorf(c);
        float fy = r - y0f, fx = c - x0f;
        int iy0 = (int)y0f, ix0 = (int)x0f;
        float wts[4] = { (1.f - fx) * (1.f - fy), fx * (1.f - fy),
                         (1.f - fx) * fy,         fx * fy };
        int cx[4] = { ix0, ix0 + 1, ix0, ix0 + 1 };
        int cy[4] = { iy0, iy0, iy0 + 1, iy0 + 1 };
        float ks[16], vs[16];
        #pragma unroll
        for (int i = 0; i < 16; ++i) { ks[i] = 0.f; vs[i] = 0.f; }
        #pragma unroll
        for (int corner = 0; corner < 4; ++corner) {
            bool vld = ((unsigned)cx[corner] < 64u) && ((unsigned)cy[corner] < 64u);
            if (!vld) continue;
            float wgt = wts[corner];
            size_t base = kvbase + (size_t)(cy[corner] * 64 + cx[corner]) * 32;
            const float4* kp = (const float4*)(kt + base);
            const float4* vp = (const float4*)(vt + base);
            #pragma unroll
            for (int j = 0; j < 4; ++j) {
                float4 kk = kp[j], vv = vp[j];
                ks[4 * j + 0] += wgt * kk.x; ks[4 * j + 1] += wgt * kk.y;
                ks[4 * j + 2] += wgt * kk.z; ks[4 * j + 3] += wgt * kk.w;
                vs[4 * j + 0] += wgt * vv.x; vs[4 * j + 1] += wgt * vv.y;
                vs[4 * j + 2] += wgt * vv.z; vs[4 * j + 3] += wgt * vv.w;
            }
        }
        float logit = 0.f;
        #pragma unroll
        for (int i = 0; i < 16; ++i)
            logit += qv[i] * (ks[i] + rpb_l[(head * 9 + n) * 16 + i]);
        float nm = fmaxf(m, logit);
        float alpha = __expf(m - nm);
        float pexp  = __expf(logit - nm);
        l = l * alpha + pexp;
        #pragma unroll
        for (int i = 0; i < 16; ++i) oacc[i] = oacc[i] * alpha + pexp * vs[i];
        m = nm;
    }
    float inv = 1.f / l;
    float* ao = ws + OFF_AOT;
    #pragma unroll
    for (int i = 0; i < 16; ++i)
        ao[(size_t)(head * 16 + i) * BHW + pix] = oacc[i] * inv;
}

// ------ k5: proj(64->256)+bias+residual, then cls head (256->80) ----
__global__ __launch_bounds__(256) void k5_proj_cls(
    const float* __restrict__ x, const float* __restrict__ bproj,
    const float* __restrict__ bcls, const float* __restrict__ wsr, float* __restrict__ out)
{
    __shared__ float tmp[DIM * 64];
    const int t = threadIdx.x;
    const int b = blockIdx.x >> 6, row = blockIdx.x & 63;
    const int p = t & 63;
    const int chunk = __builtin_amdgcn_readfirstlane(t >> 6);
    const float* ao  = wsr + OFF_AOT;
    const float* wpT = wsr + OFF_WPT;
    const float* wcT = wsr + OFF_WCT;
    const int pixcol = row * 64 + p;
    const int cb = chunk * 64;

    float acc[64];
    #pragma unroll
    for (int j = 0; j < 64; ++j) acc[j] = 0.f;
    const size_t aob = (size_t)b * HW + pixcol;
    #pragma unroll 4
    for (int cr = 0; cr < 64; ++cr) {
        float av = ao[(size_t)cr * BHW + aob];
        const float* wrow = wpT + cr * 256 + cb;
        #pragma unroll
        for (int j = 0; j < 64; ++j)
            acc[j] += av * wrow[j];
    }
    #pragma unroll
    for (int j = 0; j < 64; ++j) {
        int c = cb + j;
        tmp[c * 64 + p] = acc[j] + bproj[c] + x[(size_t)(b * DIM + c) * HW + pixcol];
    }
    __syncthreads();

    float acc2[20];
    #pragma unroll
    for (int j = 0; j < 20; ++j) acc2[j] = bcls[chunk * 20 + j];
    #pragma unroll 4
    for (int c = 0; c < 256; ++c) {
        float tv = tmp[c * 64 + p];
        const float* wrow = wcT + c * 80 + chunk * 20;
        #pragma unroll
        for (int j = 0; j < 20; ++j)
            acc2[j] += tv * wrow[j];
    }
    #pragma unroll
    for (int j = 0; j < 20; ++j)
        out[(size_t)(b * NCLS + chunk * 20 + j) * HW + pixcol] = acc2[j];
}

extern "C" void kernel_launch(void* const* d_in, const int* in_sizes, int n_in,
                              void* d_out, int out_size, void* d_ws, size_t ws_size,
                              hipStream_t stream)
{
    const float* x     = (const float*)d_in[0];
    const float* off   = (const float*)d_in[1];
    const float* g1    = (const float*)d_in[2];
    const float* b1    = (const float*)d_in[3];
    const float* wqkv  = (const float*)d_in[4];
    const float* wdw   = (const float*)d_in[5];
    const float* g2    = (const float*)d_in[6];
    const float* b2    = (const float*)d_in[7];
    const float* woff  = (const float*)d_in[8];
    const float* boff  = (const float*)d_in[9];
    const float* rpb   = (const float*)d_in[10];
    const float* wproj = (const float*)d_in[11];
    const float* bproj = (const float*)d_in[12];
    const float* wcls  = (const float*)d_in[13];
    const float* bcls  = (const float*)d_in[14];
    float* ws  = (float*)d_ws;
    float* out = (float*)d_out;

    hipLaunchKernelGGL(k0a_transpose, dim3(256), dim3(256), 0, stream, wqkv, g1, wproj, wcls, ws);
    hipLaunchKernelGGL(k0b_ab,        dim3(1),   dim3(192), 0, stream, wqkv, g1, b1, woff, ws);
    hipLaunchKernelGGL(k0c_stats,     dim3(512), dim3(256), 0, stream, x, ws);
    hipLaunchKernelGGL(k1_gemm,       dim3(1024), dim3(256), 0, stream, x, ws);
    hipLaunchKernelGGL(k2_off_feat,   dim3(1024), dim3(256), 0, stream, wdw, g2, b2, ws);
    hipLaunchKernelGGL(k3_pred_off,   dim3(1024), dim3(256), 0, stream, boff, off, ws);
    hipLaunchKernelGGL(k4_attn,       dim3(512), dim3(256), 0, stream, rpb, ws);
    hipLaunchKernelGGL(k5_proj_cls,   dim3(512), dim3(256), 0, stream, x, bproj, bcls, ws, out);
}

// Round 4
// 309.411 us; speedup vs baseline: 1.7997x; 1.1075x over previous
//
#include <hip/hip_runtime.h>
#include <math.h>

// Problem constants
#define BB   8
#define HW   4096
#define BHW  32768
#define DIM  256
#define CR   64
#define GC   32
#define NHD  4
#define HC   16
#define NTAP 9
#define NCLS 80

// workspace layout (float offsets)
#define OFF_QP   0u          // q planar   [B][64][H][W]        2,097,152
#define OFF_QT   2097152u    // (unused)                        2,097,152
#define OFF_KT   4194304u    // k pix-major[BG][HW][32]         2,097,152
#define OFF_VT   6291456u    // v pix-major[BG][HW][32]         2,097,152
#define OFF_T    8388608u    // t planar   [BG][32][H][W]       2,097,152
// --- overlap region: inside OFF_T's span, used only BEFORE k2 writes T ---
#define OFF_WQT  8388608u    // wqkv^T * g1  [256][192]         49,152
#define OFF_AB   8437760u    // A[192], B[192]                  384
#define OFF_STAT 8438144u    // m[32768], rs[32768]             65,536
// ------------------------------------------------------------------------
#define OFF_OFFB 10485760u   // off planar [BG][18][H][W]       1,179,648
#define OFF_AOT  11665408u   // attn out   [64][B*HW] planar    2,097,152
#define OFF_WPT  13762560u   // wproj^T [64][256]               16,384
#define OFF_WCT  13778944u   // wcls^T  [256][80]               20,480
#define OFF_WFT  13799424u   // woff^T  [9][32][18]             5,184

// ---------------- k0a: weight transposes ----------------
__global__ __launch_bounds__(256) void k0a_transpose(
    const float* __restrict__ wqkv, const float* __restrict__ g1,
    const float* __restrict__ wproj, const float* __restrict__ wcls,
    float* __restrict__ ws)
{
    const int c = blockIdx.x;   // 0..255
    const int t = threadIdx.x;
    if (t < 192) ws[OFF_WQT + c * 192 + t] = wqkv[t * 256 + c] * g1[c];
    if (c < 64)  ws[OFF_WPT + c * 256 + t] = wproj[t * 64 + c];
    if (t < 80)  ws[OFF_WCT + c * 80 + t]  = wcls[t * 256 + c];
}

// ---------------- k0b: A/B LN-fold vectors + woff transpose ----------------
__global__ __launch_bounds__(192) void k0b_ab(
    const float* __restrict__ wqkv, const float* __restrict__ g1,
    const float* __restrict__ b1, const float* __restrict__ woff,
    float* __restrict__ ws)
{
    const int t = threadIdx.x; // 0..191
    float a = 0.f, bb = 0.f;
    for (int c = 0; c < 256; ++c) {
        float w = wqkv[t * 256 + c];
        a += w * g1[c]; bb += w * b1[c];
    }
    ws[OFF_AB + t] = a;
    ws[OFF_AB + 192 + t] = bb;
    for (int pair = t; pair < 288; pair += 192) {
        int wo = pair >> 5, ic = pair & 31;
        for (int o = 0; o < 18; ++o)
            ws[OFF_WFT + (wo * 32 + ic) * 18 + o] = woff[(o * 32 + ic) * 9 + wo];
    }
}

// ---------------- k0c: per-pixel LN stats ----------------
__global__ __launch_bounds__(256) void k0c_stats(
    const float* __restrict__ x, float* __restrict__ ws)
{
    __shared__ float psum[256], psq[256];
    const int t = threadIdx.x;
    const int b = blockIdx.x >> 6, row = blockIdx.x & 63;
    const int p = t & 63, q4 = t >> 6;
    const int colbase = row * 64 + p;
    float s = 0.f, ss = 0.f;
    for (int i = 0; i < 64; ++i) {
        int c = q4 * 64 + i;
        float v = x[(size_t)(b * DIM + c) * HW + colbase];
        s += v; ss += v * v;
    }
    psum[t] = s; psq[t] = ss;
    __syncthreads();
    if (t < 64) {
        float S = psum[t] + psum[64 + t] + psum[128 + t] + psum[192 + t];
        float Q = psq[t] + psq[64 + t] + psq[128 + t] + psq[192 + t];
        float m = S * (1.f / 256.f);
        float v = Q * (1.f / 256.f) - m * m;
        float* stat = ws + OFF_STAT;
        int gp = b * HW + row * 64 + t;
        stat[gp] = m;
        stat[BHW + gp] = rsqrtf(v + 1e-5f);
    }
}

// ---------------- k1: QKV GEMM (LN folded; coalesced epilogue) ----------------
// grid 1024: mhalf=blk>>9 (96 outputs each), (b,row)=blk&511. block 256.
__global__ __launch_bounds__(256) void k1_gemm(
    const float* __restrict__ x, float* __restrict__ ws)
{
    __shared__ float smem[8192];     // 2x 16KB staging; reused as 64x97 transpose tile
    const int t = threadIdx.x;
    const int mhalf = blockIdx.x >> 9;
    const int rb = blockIdx.x & 511;
    const int b = rb >> 6, row = rb & 63;
    const int p = t & 63;
    const int og = __builtin_amdgcn_readfirstlane(t >> 6);
    const int obase = mhalf * 96 + og * 24;
    const float* wqT = ws + OFF_WQT;
    const float* AB  = ws + OFF_AB;
    const float* stat = ws + OFF_STAT;
    const size_t xbase = (size_t)b * DIM * HW + row * 64;

    float acc[24];
    #pragma unroll
    for (int j = 0; j < 24; ++j) acc[j] = 0.f;

    #pragma unroll
    for (int j = 0; j < 4; ++j) {
        int idx4 = t + j * 256;
        int c = idx4 >> 4, p4 = (idx4 & 15) << 2;
        float4 v = *(const float4*)&x[xbase + (size_t)c * HW + p4];
        *(float4*)&smem[c * 64 + p4] = v;
    }
    __syncthreads();

    for (int kt = 0; kt < 4; ++kt) {
        const int cur = kt & 1;
        float4 pf[4];
        if (kt < 3) {
            #pragma unroll
            for (int j = 0; j < 4; ++j) {
                int idx4 = t + j * 256;
                int c = idx4 >> 4, p4 = (idx4 & 15) << 2;
                pf[j] = *(const float4*)&x[xbase + (size_t)((kt + 1) * 64 + c) * HW + p4];
            }
        }
        const float* wb = wqT + (size_t)kt * 64 * 192 + obase;
        #pragma unroll 8
        for (int c = 0; c < 64; ++c) {
            float xv = smem[cur * 4096 + c * 64 + p];
            #pragma unroll
            for (int j = 0; j < 24; ++j)
                acc[j] += wb[c * 192 + j] * xv;
        }
        if (kt < 3) {
            #pragma unroll
            for (int j = 0; j < 4; ++j) {
                int idx4 = t + j * 256;
                int c = idx4 >> 4, p4 = (idx4 & 15) << 2;
                *(float4*)&smem[(cur ^ 1) * 4096 + c * 64 + p4] = pf[j];
            }
            __syncthreads();
        }
    }
    __syncthreads();

    const int colbase = row * 64 + p;
    const int gp = b * HW + colbase;
    const float m = stat[gp], rsv = stat[BHW + gp];
    #pragma unroll
    for (int j = 0; j < 24; ++j) {
        int o = obase + j;
        smem[p * 97 + og * 24 + j] = rsv * (acc[j] - m * AB[o]) + AB[192 + o];
    }
    __syncthreads();

    float* qp  = ws + OFF_QP;
    float* ktb = ws + OFF_KT;
    float* vtb = ws + OFF_VT;
    const int colrow = row * 64;
    if (mhalf == 0) {
        #pragma unroll
        for (int it = 0; it < 16; ++it) {
            int idx = it * 256 + t;
            int o = idx >> 6, px = idx & 63;
            qp[(size_t)(b * 64 + o) * HW + colrow + px] = smem[px * 97 + o];
        }
        #pragma unroll
        for (int it = 0; it < 8; ++it) {
            int idx = it * 256 + t;
            int px = idx >> 5, ch = idx & 31;
            ktb[(((size_t)(b * 2) * HW) + colrow + px) * 32 + ch] = smem[px * 97 + 64 + ch];
        }
    } else {
        #pragma unroll
        for (int it = 0; it < 8; ++it) {
            int idx = it * 256 + t;
            int px = idx >> 5, ch = idx & 31;
            ktb[(((size_t)(b * 2 + 1) * HW) + colrow + px) * 32 + ch] = smem[px * 97 + ch];
        }
        #pragma unroll
        for (int it = 0; it < 8; ++it) {
            int idx = it * 256 + t;
            int px = idx >> 5, ch = idx & 31;
            vtb[(((size_t)(b * 2) * HW) + colrow + px) * 32 + ch] = smem[px * 97 + 32 + ch];
        }
        #pragma unroll
        for (int it = 0; it < 8; ++it) {
            int idx = it * 256 + t;
            int px = idx >> 5, ch = idx & 31;
            vtb[(((size_t)(b * 2 + 1) * HW) + colrow + px) * 32 + ch] = smem[px * 97 + 64 + ch];
        }
    }
}

// ------- k2: depthwise 3x3 + LN(32) + GELU, channel-split across waves -------
__global__ __launch_bounds__(256) void k2_off_feat(
    const float* __restrict__ wdw, const float* __restrict__ g2, const float* __restrict__ b2,
    float* __restrict__ ws)
{
    __shared__ float rsum[4][64], rsq[4][64], smv[64], srv[64];
    const int t = threadIdx.x;
    const int bg = blockIdx.x >> 6, row = blockIdx.x & 63;
    const int p = t & 63;
    const int cq = __builtin_amdgcn_readfirstlane(t >> 6);
    const int b = bg >> 1, g = bg & 1;
    const float* qp = ws + OFF_QP;
    float vals[8];
    float s = 0.f, ss = 0.f;
    #pragma unroll
    for (int i = 0; i < 8; ++i) {
        int ch = cq * 8 + i;
        const float* plane = qp + (size_t)(b * 64 + g * 32 + ch) * HW;
        float a = 0.f;
        #pragma unroll
        for (int dy = 0; dy < 3; ++dy) {
            int y = row + dy - 1;
            if ((unsigned)y >= 64u) continue;
            #pragma unroll
            for (int dx = 0; dx < 3; ++dx) {
                int xx = p + dx - 1;
                bool vld = (unsigned)xx < 64u;
                float q = plane[y * 64 + (vld ? xx : 0)];
                a += (vld ? q : 0.f) * wdw[ch * 9 + dy * 3 + dx];
            }
        }
        vals[i] = a; s += a; ss += a * a;
    }
    rsum[cq][p] = s; rsq[cq][p] = ss;
    __syncthreads();
    if (t < 64) {
        float S = rsum[0][t] + rsum[1][t] + rsum[2][t] + rsum[3][t];
        float Q = rsq[0][t] + rsq[1][t] + rsq[2][t] + rsq[3][t];
        float m = S * (1.f / 32.f);
        float v = Q * (1.f / 32.f) - m * m;
        smv[t] = m; srv[t] = rsqrtf(v + 1e-5f);
    }
    __syncthreads();
    float m = smv[p], rv = srv[p];
    float* tb = ws + OFF_T;
    #pragma unroll
    for (int i = 0; i < 8; ++i) {
        int ch = cq * 8 + i;
        float u = (vals[i] - m) * rv * g2[ch] + b2[ch];
        float ge = 0.5f * u * (1.f + erff(u * 0.70710678118654752f));
        tb[(size_t)(bg * 32 + ch) * HW + row * 64 + p] = ge;
    }
}

// ------- k3: 3x3 conv 32->18 + tanh*5 + base offset, ic-split across waves -------
__global__ __launch_bounds__(256) void k3_pred_off(
    const float* __restrict__ boff, const float* __restrict__ off_in,
    float* __restrict__ ws)
{
    __shared__ float part[4 * 18 * 64];
    const int t = threadIdx.x;
    const int bg = blockIdx.x >> 6, row = blockIdx.x & 63;
    const int p = t & 63;
    const int icq = __builtin_amdgcn_readfirstlane(t >> 6);
    const int b = bg >> 1;
    const float* tb = ws + OFF_T;
    const float* wfT = ws + OFF_WFT;
    float acc[18];
    #pragma unroll
    for (int o = 0; o < 18; ++o) acc[o] = 0.f;
    #pragma unroll
    for (int dy = 0; dy < 3; ++dy) {
        int y = row + dy - 1;
        if ((unsigned)y >= 64u) continue;
        #pragma unroll
        for (int dx = 0; dx < 3; ++dx) {
            int xx = p + dx - 1;
            bool vld = (unsigned)xx < 64u;
            int xc = vld ? xx : 0;
            int wo = dy * 3 + dx;
            #pragma unroll
            for (int i = 0; i < 8; ++i) {
                int ic = icq * 8 + i;
                float tv = tb[(size_t)(bg * 32 + ic) * HW + y * 64 + xc];
                tv = vld ? tv : 0.f;
                const float* wrow = wfT + (wo * 32 + ic) * 18;
                #pragma unroll
                for (int o = 0; o < 18; ++o)
                    acc[o] += tv * wrow[o];
            }
        }
    }
    #pragma unroll
    for (int o = 0; o < 18; ++o) part[(icq * 18 + o) * 64 + p] = acc[o];
    __syncthreads();
    float* ob = ws + OFF_OFFB;
    #pragma unroll
    for (int r = 0; r < 5; ++r) {
        int idx = t + r * 256;
        if (idx < 1152) {
            int o = idx >> 6, p2 = idx & 63;
            float v = part[o * 64 + p2] + part[(18 + o) * 64 + p2]
                    + part[(36 + o) * 64 + p2] + part[(54 + o) * 64 + p2] + boff[o];
            v = tanhf(v) * 5.0f + off_in[(size_t)(b * 18 + o) * HW + row * 64 + p2];
            ob[(size_t)(bg * 18 + o) * HW + row * 64 + p2] = v;
        }
    }
}

// ---- k4: deformable gather + online-softmax attn ----
// XCD-affine: b = blk & 7 (blk%8 tracks XCD -> per-XCD KV working set = 2 MB < L2)
// grid 1024, block 256; wave = head; lane bit5 = channel half (8 ch per lane),
// bits 0-4 = pixel within a 32-pixel chunk. Logit combined via shfl_xor(32).
__global__ __launch_bounds__(256) void k4_attn(
    const float* __restrict__ rpb, float* __restrict__ ws)
{
    __shared__ float rpb_l[NHD * NTAP * HC];
    for (int i = threadIdx.x; i < NHD * NTAP * HC; i += 256) rpb_l[i] = rpb[i];
    __syncthreads();

    const int t = threadIdx.x;
    const int head = __builtin_amdgcn_readfirstlane(t >> 6);
    const int lane = t & 63;
    const int chh = (lane >> 5) & 1;
    const int pxl = lane & 31;
    const int b = blockIdx.x & 7;
    const int chunk = blockIdx.x >> 3;       // 0..127
    const int hw = chunk * 32 + pxl;
    const int pix = b * HW + hw;
    const int g = head >> 1, sub = head & 1;
    const int bg = b * 2 + g;
    const float* qp = ws + OFF_QP;
    const float* kt = ws + OFF_KT;
    const float* vt = ws + OFF_VT;
    const float* ob = ws + OFF_OFFB;

    float qv[8];
    #pragma unroll
    for (int i = 0; i < 8; ++i)
        qv[i] = qp[(size_t)(b * 64 + head * 16 + chh * 8 + i) * HW + hw] * 0.25f;

    float rr[NTAP], cc[NTAP];
    #pragma unroll
    for (int n = 0; n < NTAP; ++n) {
        rr[n] = ob[(size_t)(bg * 18 + 2 * n) * HW + hw];
        cc[n] = ob[(size_t)(bg * 18 + 2 * n + 1) * HW + hw];
    }

    float m = -INFINITY, l = 0.f, oacc[8];
    #pragma unroll
    for (int i = 0; i < 8; ++i) oacc[i] = 0.f;

    const size_t kvbase = (size_t)bg * HW * 32 + sub * 16 + chh * 8;
    const float* rpb_base = rpb_l + head * 9 * 16 + chh * 8;
    for (int n = 0; n < NTAP; ++n) {
        float r = rr[n], c = cc[n];
        float y0f = floorf(r), x0f = floorf(c);
        float fy = r - y0f, fx = c - x0f;
        int iy0 = (int)y0f, ix0 = (int)x0f;
        float wts[4] = { (1.f - fx) * (1.f - fy), fx * (1.f - fy),
                         (1.f - fx) * fy,         fx * fy };
        int cx[4] = { ix0, ix0 + 1, ix0, ix0 + 1 };
        int cy[4] = { iy0, iy0, iy0 + 1, iy0 + 1 };
        float ks[8], vs[8];
        #pragma unroll
        for (int i = 0; i < 8; ++i) { ks[i] = 0.f; vs[i] = 0.f; }
        #pragma unroll
        for (int corner = 0; corner < 4; ++corner) {
            bool vld = ((unsigned)cx[corner] < 64u) && ((unsigned)cy[corner] < 64u);
            if (!vld) continue;
            float wgt = wts[corner];
            size_t base = kvbase + (size_t)(cy[corner] * 64 + cx[corner]) * 32;
            const float4* kp = (const float4*)(kt + base);
            const float4* vp = (const float4*)(vt + base);
            #pragma unroll
            for (int j = 0; j < 2; ++j) {
                float4 kk = kp[j], vv = vp[j];
                ks[4 * j + 0] += wgt * kk.x; ks[4 * j + 1] += wgt * kk.y;
                ks[4 * j + 2] += wgt * kk.z; ks[4 * j + 3] += wgt * kk.w;
                vs[4 * j + 0] += wgt * vv.x; vs[4 * j + 1] += wgt * vv.y;
                vs[4 * j + 2] += wgt * vv.z; vs[4 * j + 3] += wgt * vv.w;
            }
        }
        float part = 0.f;
        #pragma unroll
        for (int i = 0; i < 8; ++i)
            part += qv[i] * (ks[i] + rpb_base[n * 16 + i]);
        float logit = part + __shfl_xor(part, 32, 64);
        float nm = fmaxf(m, logit);
        float alpha = __expf(m - nm);
        float pexp  = __expf(logit - nm);
        l = l * alpha + pexp;
        #pragma unroll
        for (int i = 0; i < 8; ++i) oacc[i] = oacc[i] * alpha + pexp * vs[i];
        m = nm;
    }
    float inv = 1.f / l;
    float* ao = ws + OFF_AOT;
    #pragma unroll
    for (int i = 0; i < 8; ++i)
        ao[(size_t)(head * 16 + chh * 8 + i) * BHW + pix] = oacc[i] * inv;
}

// ------ k5: proj(64->256)+bias+residual, then cls head (256->80) ----
__global__ __launch_bounds__(256) void k5_proj_cls(
    const float* __restrict__ x, const float* __restrict__ bproj,
    const float* __restrict__ bcls, const float* __restrict__ wsr, float* __restrict__ out)
{
    __shared__ float tmp[DIM * 64];
    const int t = threadIdx.x;
    const int b = blockIdx.x >> 6, row = blockIdx.x & 63;
    const int p = t & 63;
    const int chunk = __builtin_amdgcn_readfirstlane(t >> 6);
    const float* ao  = wsr + OFF_AOT;
    const float* wpT = wsr + OFF_WPT;
    const float* wcT = wsr + OFF_WCT;
    const int pixcol = row * 64 + p;
    const int cb = chunk * 64;

    float acc[64];
    #pragma unroll
    for (int j = 0; j < 64; ++j) acc[j] = 0.f;
    const size_t aob = (size_t)b * HW + pixcol;
    #pragma unroll 4
    for (int cr = 0; cr < 64; ++cr) {
        float av = ao[(size_t)cr * BHW + aob];
        const float* wrow = wpT + cr * 256 + cb;
        #pragma unroll
        for (int j = 0; j < 64; ++j)
            acc[j] += av * wrow[j];
    }
    #pragma unroll
    for (int j = 0; j < 64; ++j) {
        int c = cb + j;
        tmp[c * 64 + p] = acc[j] + bproj[c] + x[(size_t)(b * DIM + c) * HW + pixcol];
    }
    __syncthreads();

    float acc2[20];
    #pragma unroll
    for (int j = 0; j < 20; ++j) acc2[j] = bcls[chunk * 20 + j];
    #pragma unroll 4
    for (int c = 0; c < 256; ++c) {
        float tv = tmp[c * 64 + p];
        const float* wrow = wcT + c * 80 + chunk * 20;
        #pragma unroll
        for (int j = 0; j < 20; ++j)
            acc2[j] += tv * wrow[j];
    }
    #pragma unroll
    for (int j = 0; j < 20; ++j)
        out[(size_t)(b * NCLS + chunk * 20 + j) * HW + pixcol] = acc2[j];
}

extern "C" void kernel_launch(void* const* d_in, const int* in_sizes, int n_in,
                              void* d_out, int out_size, void* d_ws, size_t ws_size,
                              hipStream_t stream)
{
    const float* x     = (const float*)d_in[0];
    const float* off   = (const float*)d_in[1];
    const float* g1    = (const float*)d_in[2];
    const float* b1    = (const float*)d_in[3];
    const float* wqkv  = (const float*)d_in[4];
    const float* wdw   = (const float*)d_in[5];
    const float* g2    = (const float*)d_in[6];
    const float* b2    = (const float*)d_in[7];
    const float* woff  = (const float*)d_in[8];
    const float* boff  = (const float*)d_in[9];
    const float* rpb   = (const float*)d_in[10];
    const float* wproj = (const float*)d_in[11];
    const float* bproj = (const float*)d_in[12];
    const float* wcls  = (const float*)d_in[13];
    const float* bcls  = (const float*)d_in[14];
    float* ws  = (float*)d_ws;
    float* out = (float*)d_out;

    hipLaunchKernelGGL(k0a_transpose, dim3(256), dim3(256), 0, stream, wqkv, g1, wproj, wcls, ws);
    hipLaunchKernelGGL(k0b_ab,        dim3(1),   dim3(192), 0, stream, wqkv, g1, b1, woff, ws);
    hipLaunchKernelGGL(k0c_stats,     dim3(512), dim3(256), 0, stream, x, ws);
    hipLaunchKernelGGL(k1_gemm,       dim3(1024), dim3(256), 0, stream, x, ws);
    hipLaunchKernelGGL(k2_off_feat,   dim3(1024), dim3(256), 0, stream, wdw, g2, b2, ws);
    hipLaunchKernelGGL(k3_pred_off,   dim3(1024), dim3(256), 0, stream, boff, off, ws);
    hipLaunchKernelGGL(k4_attn,       dim3(1024), dim3(256), 0, stream, rpb, ws);
    hipLaunchKernelGGL(k5_proj_cls,   dim3(512), dim3(256), 0, stream, x, bproj, bcls, ws, out);
}